// Round 9
// baseline (155.216 us; speedup 1.0000x reference)
//
#include <hip/hip_runtime.h>
#include <hip/hip_bf16.h>
#include <math.h>

// Problem constants
#define LQ 196      // spatial tokens (14x14)
#define NH 12       // heads
#define DH 64       // head dim
#define CC 768      // output channels
#define NPAIR 28    // 4 n * 7 t' pairs per half
#define PQ ((size_t)LQ * LQ)   // 38416
#define NW 729      // (2*14-1)^2 w rows

#define KROWS2 224  // 14*16 (k padded so both k-halves run 7 uniform tiles)
#define LPITCH 72   // shorts per Ks LDS row (64 + 8 pad; 4r%32 bank spread)
#define APITCH 232  // out-kernel A LDS pitch

// ws layout (in shorts):
//   Pm  : 2 hg x 56 planes x PQ bf16 partial head-sums (8.6 MB)
//   Wb  : W1|W2 bf16
//   Kb  : K bf16, layout [nt][h][l<196][64]
#define PM_SHORTS ((size_t)2 * 56 * PQ)
#define WB_OFF    PM_SHORTS
#define WB_SHORTS ((size_t)2 * NW * CC)
#define KB_OFF    (WB_OFF + WB_SHORTS)

typedef short short8 __attribute__((ext_vector_type(8)));
typedef float f32x4  __attribute__((ext_vector_type(4)));

__device__ __forceinline__ short f2bf(float f) {
    __hip_bfloat16 h = __float2bfloat16(f);
    return __builtin_bit_cast(short, h);
}

// ---------------------------------------------------------------------------
// PREP (one launch): zero Out l=0 rows | W1,W2 -> bf16 | K -> bf16 head-major
#define ZBLK 96
#define WBLK 1094                    // ceil(2*NW*CC/4 / 256)
#define KBLK 4704                    // 32*12*196*16 / 256
__global__ __launch_bounds__(256) void prep_kernel(
    const float* __restrict__ K,
    const float* __restrict__ W1, const float* __restrict__ W2,
    short* __restrict__ Wb, short* __restrict__ Kb,
    float* __restrict__ Out)
{
    int b = blockIdx.x, tid = threadIdx.x;
    if (b < ZBLK) {
        int e = b * 256 + tid;                        // < 24576
        int nt = e / CC, c = e % CC;
        Out[(size_t)nt * 197 * CC + c] = 0.f;
    } else if (b < ZBLK + WBLK) {
        int e4 = (b - ZBLK) * 256 + tid;
        const int N4 = NW * CC / 4;                   // 139968
        if (e4 < 2 * N4) {
            const float* src = (e4 < N4) ? (W1 + (size_t)e4 * 4)
                                         : (W2 + (size_t)(e4 - N4) * 4);
            float4 f = *(const float4*)src;
            short4 v = {f2bf(f.x), f2bf(f.y), f2bf(f.z), f2bf(f.w)};
            *(short4*)(Wb + (size_t)e4 * 4) = v;
        }
    } else {
        int loc = (b - ZBLK - WBLK) * 256 + tid;      // < 1204224
        int c4 = loc & 15;
        int r1 = loc >> 4;
        int l  = r1 % LQ;
        int r2 = r1 / LQ;
        int h  = r2 % NH;
        int nt = r2 / NH;
        const float* s = K + (size_t)((nt * 197 + 1 + l) * NH + h) * DH + c4 * 4;
        float4 f = *(const float4*)s;
        short4 v = {f2bf(f.x), f2bf(f.y), f2bf(f.z), f2bf(f.w)};
        *(short4*)(Kb + (size_t)loc * 4) = v;
    }
}

// ---------------------------------------------------------------------------
// ATTN, head-split (R9): grid 784 = 8 xcd x 98; block = (plane, qg, hg).
// Each block runs SIX serial heads (hg*6..hg*6+5) — halves the R8 serial
// chain and doubles block-level parallelism. Writes PARTIAL head-sum plane
// Pm[hg][plane]; out-kernel adds the two partials during A-staging.
// Double-buffered K (VGPR prefetch), one barrier/head, red[] ping-pong.
// Q fragments read directly from fp32 global (2 float4/lane, L2-hot).
__global__ __launch_bounds__(256) void attn_fused_kernel(
    const float* __restrict__ Qf, const short* __restrict__ Kb,
    short* __restrict__ Pm)
{
    int bid  = blockIdx.x;
    int xcd  = bid & 7;
    int slot = bid >> 3;                 // 0..97
    int plane = xcd + 8 * (slot / 14);   // 0..55 = hf*28 + p (7 qg x 2 hg share)
    int sub   = slot % 14;
    int qg = sub % 7, hg = sub / 7;
    int p  = plane % NPAIR;
    int hf = plane / NPAIR;              // 0: (q[t+1],k[t])  1: (q[t],k[t+1])
    int n = p / 7, i = p % 7;
    int tq = hf ? i     : i + 1;
    int tk = hf ? i + 1 : i;

    __shared__ __align__(16) short Ks[2][KROWS2 * LPITCH];  // 64.5 KB
    __shared__ __align__(16) short Ps[32 * LQ];             // 12.25 KB
    __shared__ float red[2][2][2][16];                      // [h&1][strip][khalf][row]

    int tid  = threadIdx.x;
    int wave = tid >> 6, lane = tid & 63;
    int m16  = lane & 15, q4 = lane >> 4;
    int strip = wave >> 1, khalf = wave & 1;
    int tb = khalf * 7;                  // wave's k-tile base

    // K slice for this block's 6 heads
    const short* Kh = Kb + ((size_t)(n * 8 + tk) * NH + hg * 6) * (LQ * DH);

    int qrow = qg * 32 + strip * 16 + m16;
    int qr = (qrow < LQ) ? qrow : (LQ - 1);   // clamp; rows >=196 never stored
    // Q fp32 base for this lane's fragment (head added per iteration)
    const float* qbase = Qf + (size_t)((n * 8 + tq) * 197 + 1 + qr) * (NH * DH)
                       + hg * 6 * DH + q4 * 8;

    // per-thread staging geometry: e = tid + 256*j; K src is LINEAR (k0 + 8e)
    int sr[7], sw[7];  bool sv[7];
#pragma unroll
    for (int j = 0; j < 7; ++j) {
        int e = tid + 256 * j;
        int r = e >> 3, c8 = e & 7;
        sr[j] = 8 * e;
        sw[j] = r * LPITCH + c8 * 8;
        sv[j] = (r < LQ);
    }

    // stage h=0 K + load h=0 Q fragment
    {
        short8 z = {0,0,0,0,0,0,0,0};
#pragma unroll
        for (int j = 0; j < 7; ++j) {
            short8 v = sv[j] ? *(const short8*)(Kh + sr[j]) : z;
            *(short8*)&Ks[0][sw[j]] = v;
        }
    }
    short8 qa0, qa1;
    {
        float4 f0 = *(const float4*)(qbase);
        float4 f1 = *(const float4*)(qbase + 4);
        float4 f2 = *(const float4*)(qbase + 32);
        float4 f3 = *(const float4*)(qbase + 36);
        qa0[0]=f2bf(f0.x); qa0[1]=f2bf(f0.y); qa0[2]=f2bf(f0.z); qa0[3]=f2bf(f0.w);
        qa0[4]=f2bf(f1.x); qa0[5]=f2bf(f1.y); qa0[6]=f2bf(f1.z); qa0[7]=f2bf(f1.w);
        qa1[0]=f2bf(f2.x); qa1[1]=f2bf(f2.y); qa1[2]=f2bf(f2.z); qa1[3]=f2bf(f2.w);
        qa1[4]=f2bf(f3.x); qa1[5]=f2bf(f3.y); qa1[6]=f2bf(f3.z); qa1[7]=f2bf(f3.w);
    }
    __syncthreads();

    f32x4 pm[7];
#pragma unroll
    for (int t = 0; t < 7; ++t) pm[t] = (f32x4){0.f, 0.f, 0.f, 0.f};

    for (int h = 0; h < 6; ++h) {
        int cur = h & 1;

        // prefetch next head into VGPRs (overlaps compute below)
        short8 pfk[7];
        float4 pf0, pf1, pf2, pf3;
        if (h < 5) {
            const short* kn = Kh + (size_t)(h + 1) * (LQ * DH);
            short8 z = {0,0,0,0,0,0,0,0};
#pragma unroll
            for (int j = 0; j < 7; ++j)
                pfk[j] = sv[j] ? *(const short8*)(kn + sr[j]) : z;
            const float* qn = qbase + (h + 1) * DH;
            pf0 = *(const float4*)(qn);
            pf1 = *(const float4*)(qn + 4);
            pf2 = *(const float4*)(qn + 32);
            pf3 = *(const float4*)(qn + 36);
        }

        // MFMA on current buffer
        f32x4 acc[7];
#pragma unroll
        for (int t = 0; t < 7; ++t) acc[t] = (f32x4){0.f, 0.f, 0.f, 0.f};
#pragma unroll
        for (int t = 0; t < 7; ++t) {
            const short* kp = &Ks[cur][((tb + t) * 16 + m16) * LPITCH + q4 * 8];
            short8 b0 = *(const short8*)(kp);
            short8 b1 = *(const short8*)(kp + 32);
            acc[t] = __builtin_amdgcn_mfma_f32_16x16x32_bf16(qa0, b0, acc[t], 0, 0, 0);
            acc[t] = __builtin_amdgcn_mfma_f32_16x16x32_bf16(qa1, b1, acc[t], 0, 0, 0);
        }

        // exp (no max-sub: logits ~N(0,1)) + wave-partial row sums
        float v4[4] = {0.f, 0.f, 0.f, 0.f};
#pragma unroll
        for (int t = 0; t < 7; ++t) {
            int k = (tb + t) * 16 + m16;
#pragma unroll
            for (int r = 0; r < 4; ++r) {
                float pe = (k < LQ) ? __expf(acc[t][r] * 0.125f) : 0.f;
                acc[t][r] = pe;
                v4[r] += pe;
            }
        }
#pragma unroll
        for (int r = 0; r < 4; ++r) {
            v4[r] += __shfl_xor(v4[r], 1, 64);
            v4[r] += __shfl_xor(v4[r], 2, 64);
            v4[r] += __shfl_xor(v4[r], 4, 64);
            v4[r] += __shfl_xor(v4[r], 8, 64);
        }
        if (m16 == 0) {
#pragma unroll
            for (int r = 0; r < 4; ++r) red[cur][strip][khalf][q4 * 4 + r] = v4[r];
        }

        // commit prefetch into the other buffer + convert Q
        if (h < 5) {
#pragma unroll
            for (int j = 0; j < 7; ++j) *(short8*)&Ks[1 - cur][sw[j]] = pfk[j];
        }
        __syncthreads();
        // safe: Ks[cur] reads done pre-barrier; next head writes Ks[cur] only
        // after ITS barrier; red ping-pong by h&1.

        float inv[4];
#pragma unroll
        for (int r = 0; r < 4; ++r)
            inv[r] = 1.0f / (12.0f * (red[cur][strip][0][q4 * 4 + r] +
                                      red[cur][strip][1][q4 * 4 + r]));
#pragma unroll
        for (int t = 0; t < 7; ++t)
#pragma unroll
            for (int r = 0; r < 4; ++r) pm[t][r] += acc[t][r] * inv[r];

        if (h < 5) {
            qa0[0]=f2bf(pf0.x); qa0[1]=f2bf(pf0.y); qa0[2]=f2bf(pf0.z); qa0[3]=f2bf(pf0.w);
            qa0[4]=f2bf(pf1.x); qa0[5]=f2bf(pf1.y); qa0[6]=f2bf(pf1.z); qa0[7]=f2bf(pf1.w);
            qa1[0]=f2bf(pf2.x); qa1[1]=f2bf(pf2.y); qa1[2]=f2bf(pf2.z); qa1[3]=f2bf(pf2.w);
            qa1[4]=f2bf(pf3.x); qa1[5]=f2bf(pf3.y); qa1[6]=f2bf(pf3.z); qa1[7]=f2bf(pf3.w);
        }
    }

    // epilogue: partial pm -> Ps strip -> linear coalesced stores
#pragma unroll
    for (int t = 0; t < 7; ++t) {
        int k = (tb + t) * 16 + m16;
        if (k < LQ) {
#pragma unroll
            for (int r = 0; r < 4; ++r)
                Ps[(strip * 16 + q4 * 4 + r) * LQ + k] = f2bf(pm[t][r]);
        }
    }
    __syncthreads();

    int row0 = qg * 32;
    int rows = LQ - row0; if (rows > 32) rows = 32;    // qg=6 -> 4 rows
    int nb = rows * (LQ * 2);                          // bytes, mult of 16
    char* dst = (char*)(Pm + ((size_t)hg * 56 + plane) * PQ + (size_t)row0 * LQ);
    const char* sp = (const char*)Ps;
    for (int e = tid * 16; e < nb; e += 256 * 16)
        *(short8*)(dst + e) = *(const short8*)(sp + e);
}

// ---------------------------------------------------------------------------
// OUT (MFMA): per q: Out[n*8+t][c] = sum_k A1[n*7+t-1][q][k]*W1[idx(q,k)][c]
//                                  + sum_k A2[n*7+t  ][q][k]*W2[idx(q,k)][c]
// T-shifted A staging (M=32, one acc set), now summing the two hg partial
// planes; B gathered from bf16 Wb via premultiplied LDS idx table.
// grid (196, 4): y = c-quarter (12 tiles of 16, 3 per wave).
__global__ __launch_bounds__(256) void out_mfma_kernel(
    const short* __restrict__ Pm, const short* __restrict__ Wb,
    float* __restrict__ Out)
{
    int q   = blockIdx.x;
    int yb  = blockIdx.y;
    int tid = threadIdx.x;
    int wave = tid >> 6, lane = tid & 63;
    int n16 = lane & 15, q4 = lane >> 4;

    __shared__ __align__(16) short A1s[32 * APITCH];   // 14.8 KB
    __shared__ __align__(16) short A2s[32 * APITCH];
    __shared__ int idxs[224];                          // premultiplied by CC

    const short* Wb1 = Wb;
    const short* Wb2 = Wb + (size_t)NW * CC;

    int pi = q / 14, pj = q % 14;
    for (int k = tid; k < 224; k += 256) {
        int v = 0;
        if (k < LQ) { int ki = k / 14, kj = k % 14; v = (pi - ki + 13) * 27 + (pj - kj + 13); }
        idxs[k] = v * CC;
    }

    // A staging: 64 rows x 58 short4 slots; A = Pm[hg=0] + Pm[hg=1]
    for (int e = tid; e < 64 * 58; e += 256) {
        int r2 = e / 58, c4 = e % 58;
        int k4 = c4 * 4;
        int r = r2 & 31, hfsel = r2 >> 5;      // 0 -> A1s, 1 -> A2s
        int n = r >> 3, t = r & 7;
        int pl = hfsel ? t : t - 1;
        short4 v = {0, 0, 0, 0};
        if (pl >= 0 && pl <= 6 && k4 < LQ) {
            const short* s0 = Pm + (size_t)(hfsel * NPAIR + n * 7 + pl) * PQ
                                 + (size_t)q * LQ + k4;
            short4 a = *(const short4*)s0;
            short4 b = *(const short4*)(s0 + (size_t)56 * PQ);
#define BF2F(s) __builtin_bit_cast(float, (unsigned)((unsigned short)(s)) << 16)
            v.x = f2bf(BF2F(a.x) + BF2F(b.x));
            v.y = f2bf(BF2F(a.y) + BF2F(b.y));
            v.z = f2bf(BF2F(a.z) + BF2F(b.z));
            v.w = f2bf(BF2F(a.w) + BF2F(b.w));
#undef BF2F
        }
        *(short4*)((hfsel ? A2s : A1s) + r * APITCH + k4) = v;
    }
    __syncthreads();

    for (int i = 0; i < 3; ++i) {
        int nt = yb * 12 + wave * 3 + i;
        int c0 = nt * 16;
        int cn = c0 + n16;
        f32x4 acc0 = {0.f, 0.f, 0.f, 0.f}, acc1 = {0.f, 0.f, 0.f, 0.f};

        for (int ks = 0; ks < 7; ++ks) {
            int kb = ks * 32 + q4 * 8;
            short8 b1, b2;
#pragma unroll
            for (int j = 0; j < 8; ++j) {
                int o = idxs[kb + j];
                b1[j] = Wb1[o + cn];
                b2[j] = Wb2[o + cn];
            }

            short8 a10 = *(const short8*)&A1s[n16 * APITCH + kb];
            short8 a11 = *(const short8*)&A1s[(16 + n16) * APITCH + kb];
            short8 a20 = *(const short8*)&A2s[n16 * APITCH + kb];
            short8 a21 = *(const short8*)&A2s[(16 + n16) * APITCH + kb];
            acc0 = __builtin_amdgcn_mfma_f32_16x16x32_bf16(a10, b1, acc0, 0, 0, 0);
            acc0 = __builtin_amdgcn_mfma_f32_16x16x32_bf16(a20, b2, acc0, 0, 0, 0);
            acc1 = __builtin_amdgcn_mfma_f32_16x16x32_bf16(a11, b1, acc1, 0, 0, 0);
            acc1 = __builtin_amdgcn_mfma_f32_16x16x32_bf16(a21, b2, acc1, 0, 0, 0);
        }

#pragma unroll
        for (int mt = 0; mt < 2; ++mt) {
            f32x4 a = mt ? acc1 : acc0;
#pragma unroll
            for (int r = 0; r < 4; ++r) {
                int row = mt * 16 + q4 * 4 + r;     // = n*8 + t
                Out[(size_t)(row * 197 + 1 + q) * CC + cn] = a[r];
            }
        }
    }
}

// ---------------------------------------------------------------------------
extern "C" void kernel_launch(void* const* d_in, const int* in_sizes, int n_in,
                              void* d_out, int out_size, void* d_ws, size_t ws_size,
                              hipStream_t stream) {
    const float* Q  = (const float*)d_in[0];
    const float* K  = (const float*)d_in[1];
    const float* W1 = (const float*)d_in[2];
    const float* W2 = (const float*)d_in[3];
    float* Out = (float*)d_out;
    short* Pm = (short*)d_ws;                 // 8.6 MB (2 hg partials)
    short* Wb = (short*)d_ws + WB_OFF;        // 2.24 MB
    short* Kb = (short*)d_ws + KB_OFF;        // 9.63 MB

    hipLaunchKernelGGL(prep_kernel, dim3(ZBLK + WBLK + KBLK), dim3(256), 0, stream,
                       K, W1, W2, Wb, Kb, Out);
    hipLaunchKernelGGL(attn_fused_kernel, dim3(784), dim3(256), 0, stream,
                       Q, Kb, Pm);
    hipLaunchKernelGGL(out_mfma_kernel, dim3(196, 4), dim3(256), 0, stream,
                       Pm, Wb, Out);
}